// Round 1
// 1503.762 us; speedup vs baseline: 1.1763x; 1.1763x over previous
//
#include <hip/hip_runtime.h>
#include <math.h>

#define NLEV 16
#define TSIZE (1u << 19)
#define PRIME 2654435761u
#define CLAMP_V 25.133f
#define INV_2PI 0.15915494309189535f
#define CLAMP_REV 4.0000420f      // 25.133 * INV_2PI (dead zone: pre-acts are ~|0.5| rad max)
#define MT 64            // rows per block
#define SH_STRIDE 72     // 64 + 8 halves pad
#define SA_STRIDE 520    // 512 + 8 halves pad

typedef _Float16 half8_t __attribute__((ext_vector_type(8)));
typedef float f32x4 __attribute__((ext_vector_type(4)));

// packed weight fragments in d_ws: entry = 64 lanes x 8 halves = 16B/lane
// layout per entry e=(kk*NT+t)*64+lane: holds W[n = t*16 + (lane&15)][k = kk*32 + (lane>>4)*8 + j]
// W1, W2 are PRE-SCALED by 1/(2*pi) so hidden pre-acts land in revolution units for v_sin_f32.
#define W1_ENT 0                  // 2*32*64   = 4096 entries
#define W2_ENT 4096               // 16*32*64  = 32768 entries
#define W3_ENT (4096 + 32768)     // 16*24*64  = 24576 entries
#define N_ENT (4096 + 32768 + 24576)

struct ResTab { int r[NLEV]; };

// sin for |v| <= 25.14 (= 8*pi): round-to-nearest pi reduction + odd deg-11 poly.
// Kept for layer 3 only (output precision); hidden layers use hw v_sin_f32.
__device__ __forceinline__ float fast_sin(float v) {
    float n = rintf(v * 0.31830988618367f);
    float r = fmaf(n, -3.14159274101257f, v);     // v - n*PI_HI (fma-exact)
    r = fmaf(n, 8.742278012618954e-8f, r);        // - n*PI_LO
    float r2 = r * r;
    float p = fmaf(r2, -2.5050760253e-8f, 2.7557313707e-6f);
    p = fmaf(r2, p, -1.9841269830e-4f);
    p = fmaf(r2, p, 8.3333333333e-3f);
    p = fmaf(r2, p, -1.6666666667e-1f);
    float s = fmaf(r * r2, p, r);
    int ni = (int)n;
    return (ni & 1) ? -s : s;
}

// hidden activation; m is the pre-act already in REVOLUTIONS (weights/bias pre-scaled by 1/2pi)
__device__ __forceinline__ _Float16 hsin(float m) {
    m = fminf(fmaxf(m, -CLAMP_REV), CLAMP_REV);
    float t = m - rintf(m);                       // exact; t in [-0.5, 0.5]
    return (_Float16)__builtin_amdgcn_sinf(t);    // v_sin_f32: sin(2*pi*t)
}

__global__ void prep_weights(const float* __restrict__ w1, const float* __restrict__ w2,
                             const float* __restrict__ w3, _Float16* __restrict__ pack) {
    int tid = blockIdx.x * 256 + threadIdx.x;
    if (tid >= N_ENT) return;
    const float* src;
    int K, NT, e;
    float scl;
    if (tid < W2_ENT)      { src = w1; K = 64;  NT = 32; e = tid;          scl = INV_2PI; }
    else if (tid < W3_ENT) { src = w2; K = 512; NT = 32; e = tid - W2_ENT; scl = INV_2PI; }
    else                   { src = w3; K = 512; NT = 24; e = tid - W3_ENT; scl = 1.0f;   }
    int lane = e & 63;
    int rest = e >> 6;
    int t = rest % NT, kk = rest / NT;
    int nn = t * 16 + (lane & 15);
    int k0 = kk * 32 + (lane >> 4) * 8;
    const float* s = src + (size_t)nn * K + k0;
    _Float16* d = pack + (size_t)tid * 8;
#pragma unroll
    for (int j = 0; j < 8; j++) d[j] = (_Float16)(s[j] * scl);
}

__launch_bounds__(512, 4)
__global__ void fused_mlp(const float* __restrict__ gy, const float* __restrict__ gx,
                          const float* __restrict__ cam, const float* __restrict__ table,
                          const float* __restrict__ b1, const float* __restrict__ b2,
                          const float* __restrict__ b3, const _Float16* __restrict__ pack,
                          float* __restrict__ out, ResTab rt) {
    __shared__ _Float16 sH[MT * SH_STRIDE];   // 9216 B : encoded inputs (64 x 64)
    __shared__ _Float16 sA[MT * SA_STRIDE];   // 66560 B: h1, then h2 (64 x 512)
    const int tid = threadIdx.x;
    const int r0 = blockIdx.x * MT;

    // ---------------- encode: hashgrid (cols 0..31) + cam_feat (cols 32..63) ----------------
    {
        const int lev = tid & 15;        // each thread: one level, 2 rows
        const int rbase = tid >> 4;      // 0..31
        const int res = rt.r[lev];
        const float fres = (float)(res - 1);
        const int rmax = res - 1;
        const float2* tab = ((const float2*)table) + (size_t)lev * TSIZE;
#pragma unroll
        for (int i = 0; i < 2; i++) {
            const int row = rbase + i * 32;
            const int rr = r0 + row;
            float xx = fminf(fmaxf(gx[rr], 0.0f), 511.0f) / 511.0f;
            float yy = fminf(fmaxf(gy[rr], 0.0f), 511.0f) / 511.0f;
            float px = xx * fres, py = yy * fres;
            float p0x = floorf(px), p0y = floorf(py);
            float fx = px - p0x, fy = py - p0y;
            int x0 = (int)p0x, y0 = (int)p0y;
            int x1 = min(x0 + 1, rmax), y1 = min(y0 + 1, rmax);
            unsigned hy0 = (unsigned)y0 * PRIME, hy1 = (unsigned)y1 * PRIME;
            unsigned ux0 = (unsigned)x0, ux1 = (unsigned)x1;
            float2 c00 = tab[(ux0 ^ hy0) & (TSIZE - 1)];
            float2 c10 = tab[(ux1 ^ hy0) & (TSIZE - 1)];
            float2 c01 = tab[(ux0 ^ hy1) & (TSIZE - 1)];
            float2 c11 = tab[(ux1 ^ hy1) & (TSIZE - 1)];
            float w00 = (1.0f - fx) * (1.0f - fy), w10 = fx * (1.0f - fy);
            float w01 = (1.0f - fx) * fy, w11 = fx * fy;
            float f0 = c00.x * w00 + c10.x * w10 + c01.x * w01 + c11.x * w11;
            float f1 = c00.y * w00 + c10.y * w10 + c01.y * w01 + c11.y * w11;
            union { _Float16 h[2]; unsigned u; } pk;
            pk.h[0] = (_Float16)f0; pk.h[1] = (_Float16)f1;
            *(unsigned*)&sH[row * SH_STRIDE + 2 * lev] = pk.u;
        }
        const float4* cf = (const float4*)cam;
        float4 v = cf[(size_t)r0 * 8 + tid];   // 512 float4s = 64 rows x 32 floats
        int row = tid >> 3, c4 = (tid & 7) * 4;
        _Float16* d = &sH[row * SH_STRIDE + 32 + c4];
        d[0] = (_Float16)v.x; d[1] = (_Float16)v.y;
        d[2] = (_Float16)v.z; d[3] = (_Float16)v.w;
    }
    __syncthreads();

    const int wv = tid >> 6, lane = tid & 63, ln = lane & 15, q = lane >> 4;
    const half8_t* packv = (const half8_t*)pack;

    // Operands are SWAPPED vs the classic layout: mfma(W_frag, h_frag, acc) computes
    // D[n][m]; lane holds col m = ln, rows n = n_base + q*4 + r (4 CONSECUTIVE n per lane)
    // -> vectorized epilogue (b64 LDS writes / dwordx4 out stores) and float4 bias init.

    // ---------------- layer 1: (64x64) -> h1 (64x512) in sA ----------------
    {
        f32x4 acc[4][4];
#pragma unroll
        for (int nt = 0; nt < 4; nt++) {
            const float4 bb = *(const float4*)(b1 + (wv * 64 + nt * 16 + q * 4));
            f32x4 bi = {bb.x * INV_2PI, bb.y * INV_2PI, bb.z * INV_2PI, bb.w * INV_2PI};
#pragma unroll
            for (int mb = 0; mb < 4; mb++) acc[mb][nt] = bi;
        }
#pragma unroll
        for (int kk = 0; kk < 2; kk++) {
            half8_t a[4];
#pragma unroll
            for (int mb = 0; mb < 4; mb++)
                a[mb] = *(const half8_t*)&sH[(mb * 16 + ln) * SH_STRIDE + kk * 32 + q * 8];
#pragma unroll
            for (int nt = 0; nt < 4; nt++) {
                half8_t b = packv[W1_ENT + (kk * 32 + wv * 4 + nt) * 64 + lane];
#pragma unroll
                for (int mb = 0; mb < 4; mb++)
                    acc[mb][nt] = __builtin_amdgcn_mfma_f32_16x16x32_f16(b, a[mb], acc[mb][nt], 0, 0, 0);
            }
        }
#pragma unroll
        for (int nt = 0; nt < 4; nt++) {
            const int n0 = wv * 64 + nt * 16 + q * 4;
#pragma unroll
            for (int mb = 0; mb < 4; mb++) {
                union { _Float16 h[4]; uint2 u; } pk;
#pragma unroll
                for (int r = 0; r < 4; r++) pk.h[r] = hsin(acc[mb][nt][r]);
                *(uint2*)&sA[(mb * 16 + ln) * SA_STRIDE + n0] = pk.u;
            }
        }
    }
    __syncthreads();

    // ---------------- layer 2: h1 (64x512) -> h2 (64x512), in-place in sA ----------------
    {
        f32x4 acc[4][4];
#pragma unroll
        for (int nt = 0; nt < 4; nt++) {
            const float4 bb = *(const float4*)(b2 + (wv * 64 + nt * 16 + q * 4));
            f32x4 bi = {bb.x * INV_2PI, bb.y * INV_2PI, bb.z * INV_2PI, bb.w * INV_2PI};
#pragma unroll
            for (int mb = 0; mb < 4; mb++) acc[mb][nt] = bi;
        }
        for (int kk = 0; kk < 16; kk++) {
            half8_t a[4];
#pragma unroll
            for (int mb = 0; mb < 4; mb++)
                a[mb] = *(const half8_t*)&sA[(mb * 16 + ln) * SA_STRIDE + kk * 32 + q * 8];
#pragma unroll
            for (int nt = 0; nt < 4; nt++) {
                half8_t b = packv[W2_ENT + (kk * 32 + wv * 4 + nt) * 64 + lane];
#pragma unroll
                for (int mb = 0; mb < 4; mb++)
                    acc[mb][nt] = __builtin_amdgcn_mfma_f32_16x16x32_f16(b, a[mb], acc[mb][nt], 0, 0, 0);
            }
        }
        // compute sins BEFORE the in-place barrier so this VALU overlaps other waves' MFMA
        uint2 pk[4][4];
#pragma unroll
        for (int nt = 0; nt < 4; nt++)
#pragma unroll
            for (int mb = 0; mb < 4; mb++) {
                union { _Float16 h[4]; uint2 u; } t;
#pragma unroll
                for (int r = 0; r < 4; r++) t.h[r] = hsin(acc[mb][nt][r]);
                pk[nt][mb] = t.u;
            }
        __syncthreads();   // all waves finished READING h1; safe to overwrite with h2
#pragma unroll
        for (int nt = 0; nt < 4; nt++) {
            const int n0 = wv * 64 + nt * 16 + q * 4;
#pragma unroll
            for (int mb = 0; mb < 4; mb++)
                *(uint2*)&sA[(mb * 16 + ln) * SA_STRIDE + n0] = pk[nt][mb];
        }
    }
    __syncthreads();

    // ---------------- layer 3: h2 (64x512) -> out (64x384) fp32 ----------------
    {
        f32x4 acc[4][3];
#pragma unroll
        for (int nt = 0; nt < 3; nt++) {
            const float4 bb = *(const float4*)(b3 + (wv * 48 + nt * 16 + q * 4));
            f32x4 bi = {bb.x, bb.y, bb.z, bb.w};
#pragma unroll
            for (int mb = 0; mb < 4; mb++) acc[mb][nt] = bi;
        }
        for (int kk = 0; kk < 16; kk++) {
            half8_t a[4];
#pragma unroll
            for (int mb = 0; mb < 4; mb++)
                a[mb] = *(const half8_t*)&sA[(mb * 16 + ln) * SA_STRIDE + kk * 32 + q * 8];
#pragma unroll
            for (int nt = 0; nt < 3; nt++) {
                half8_t b = packv[W3_ENT + (kk * 24 + wv * 3 + nt) * 64 + lane];
#pragma unroll
                for (int mb = 0; mb < 4; mb++)
                    acc[mb][nt] = __builtin_amdgcn_mfma_f32_16x16x32_f16(b, a[mb], acc[mb][nt], 0, 0, 0);
            }
        }
#pragma unroll
        for (int nt = 0; nt < 3; nt++) {
            const int n0 = wv * 48 + nt * 16 + q * 4;
#pragma unroll
            for (int mb = 0; mb < 4; mb++) {
                float4 o;
                float vv;
                vv = fminf(fmaxf(acc[mb][nt][0], -CLAMP_V), CLAMP_V); o.x = fast_sin(vv);
                vv = fminf(fmaxf(acc[mb][nt][1], -CLAMP_V), CLAMP_V); o.y = fast_sin(vv);
                vv = fminf(fmaxf(acc[mb][nt][2], -CLAMP_V), CLAMP_V); o.z = fast_sin(vv);
                vv = fminf(fmaxf(acc[mb][nt][3], -CLAMP_V), CLAMP_V); o.w = fast_sin(vv);
                *(float4*)&out[(size_t)(r0 + mb * 16 + ln) * 384 + n0] = o;
            }
        }
    }
}

extern "C" void kernel_launch(void* const* d_in, const int* in_sizes, int n_in,
                              void* d_out, int out_size, void* d_ws, size_t ws_size,
                              hipStream_t stream) {
    const float* y   = (const float*)d_in[0];
    const float* x   = (const float*)d_in[1];
    const float* cam = (const float*)d_in[2];
    const float* tab = (const float*)d_in[3];
    const float* w1  = (const float*)d_in[4];
    const float* b1  = (const float*)d_in[5];
    const float* w2  = (const float*)d_in[6];
    const float* b2  = (const float*)d_in[7];
    const float* w3  = (const float*)d_in[8];
    const float* b3  = (const float*)d_in[9];
    float* out = (float*)d_out;
    _Float16* pack = (_Float16*)d_ws;   // needs 983040 B

    ResTab rt;
    for (int l = 0; l < NLEV; l++)
        rt.r[l] = (int)floor(32.0 * pow(1.3819, (double)l));  // matches np float64 ** (margins >= 0.03)

    prep_weights<<<dim3((N_ENT + 255) / 256), dim3(256), 0, stream>>>(w1, w2, w3, pack);

    int nblocks = in_sizes[0] / MT;   // 524288 / 64 = 8192
    fused_mlp<<<dim3(nblocks), dim3(512), 0, stream>>>(y, x, cam, tab, b1, b2, b3,
                                                       (const _Float16*)pack, out, rt);
}